// Round 8
// baseline (761.380 us; speedup 1.0000x reference)
//
#include <hip/hip_runtime.h>

#define HDIM 128
#define RDIM 64
#define NLAYERS 3

typedef unsigned int uint32;
typedef unsigned short ushort16;

typedef __attribute__((ext_vector_type(8))) short s16x8;   // 8 bf16 (4 VGPR)
typedef __attribute__((ext_vector_type(4))) float f32x4;   // MFMA acc

union U4 { uint4 u; s16x8 v; };

// round-to-nearest-even fp32 -> bf16 (as raw ushort)
__device__ __forceinline__ ushort16 f2bf_rne(float x) {
  uint32 u = __float_as_uint(x);
  u += 0x7FFFu + ((u >> 16) & 1u);
  return (ushort16)(u >> 16);
}
__device__ __forceinline__ float bf_lo(uint32 p) { return __uint_as_float(p << 16); }
__device__ __forceinline__ float bf_hi(uint32 p) { return __uint_as_float(p & 0xFFFF0000u); }

// ---------------------------------------------------------------------------
// Phase 0: init degree counts (self-loop => 1) and out (= lin_b broadcast)
// ---------------------------------------------------------------------------
__global__ void k_prep(int* __restrict__ cnt, float* __restrict__ out,
                       const float* __restrict__ lin_b, int n) {
  int stride = gridDim.x * blockDim.x;
  int i0 = blockIdx.x * blockDim.x + threadIdx.x;
  for (int i = i0; i < n; i += stride) cnt[i] = 1;
  int total = n * RDIM;
  for (int i = i0; i < total; i += stride) out[i] = lin_b[i & (RDIM - 1)];
}

// W -> transposed split-bf16 (Wt_hi/Wt_lo [c][k]) for the MFMA GEMM.
__global__ void k_wprep(const float* __restrict__ Ws, ushort16* __restrict__ Wth,
                        ushort16* __restrict__ Wtl) {
  const int lyr = blockIdx.x;
  const float* W = Ws + (size_t)lyr * HDIM * HDIM;
  ushort16* th = Wth + (size_t)lyr * HDIM * HDIM;
  ushort16* tl = Wtl + (size_t)lyr * HDIM * HDIM;
  for (int idx = threadIdx.x; idx < HDIM * HDIM; idx += blockDim.x) {
    int k = idx >> 7, c = idx & 127;
    float w = W[idx];
    uint32 u = __float_as_uint(w);
    uint32 r = u + 0x7FFFu + ((u >> 16) & 1u);
    float hf = __uint_as_float((r >> 16) << 16);
    th[c * HDIM + k] = (ushort16)(r >> 16);
    tl[c * HDIM + k] = f2bf_rne(w - hf);
  }
}

// 4 edges/thread, int4 loads (no-return atomics have no dependent chain).
__global__ void k_count(const int* __restrict__ dst, int* __restrict__ cnt, int e) {
  int i0 = (blockIdx.x * blockDim.x + threadIdx.x) * 4;
  if (i0 + 3 < e) {
    int4 d4 = *(const int4*)(dst + i0);
    atomicAdd(&cnt[d4.x], 1);
    atomicAdd(&cnt[d4.y], 1);
    atomicAdd(&cnt[d4.z], 1);
    atomicAdd(&cnt[d4.w], 1);
  } else {
    for (int i = i0; i < e; ++i) atomicAdd(&cnt[dst[i]], 1);
  }
}

// ---------------------------------------------------------------------------
// Two-level parallel exclusive scan over cnt[] -> rowptr/cursor (+ dis fused).
// ---------------------------------------------------------------------------
__global__ __launch_bounds__(1024) void k_scan1(const int* __restrict__ cnt,
                                                int* __restrict__ bsum, int n) {
  __shared__ int red[16];
  int tid = threadIdx.x;
  int gid = blockIdx.x * 1024 + tid;
  int v = (gid < n) ? cnt[gid] : 0;
#pragma unroll
  for (int off = 1; off < 64; off <<= 1) v += __shfl_xor(v, off);
  if ((tid & 63) == 0) red[tid >> 6] = v;
  __syncthreads();
  if (tid < 16) {
    int s = red[tid];
#pragma unroll
    for (int off = 1; off < 16; off <<= 1) s += __shfl_xor(s, off, 16);
    if (tid == 0) bsum[blockIdx.x] = s;
  }
}

__global__ __launch_bounds__(64) void k_scan2(const int* __restrict__ bsum,
                                              int* __restrict__ boff,
                                              int* __restrict__ rowptr,
                                              int nb, int n) {
  int lane = threadIdx.x;
  int carry = 0;
  for (int base = 0; base < nb; base += 64) {
    int i = base + lane;
    int v = (i < nb) ? bsum[i] : 0;
    int incl = v;
#pragma unroll
    for (int off = 1; off < 64; off <<= 1) {
      int t = __shfl_up(incl, off);
      if (lane >= off) incl += t;
    }
    if (i < nb) boff[i] = carry + incl - v;
    carry += __shfl(incl, 63);
  }
  if (lane == 0) rowptr[n] = carry;
}

// Level 3: rowptr/cursor/dis; self-loop pre-placed at slot 0 of each bucket.
__global__ __launch_bounds__(1024) void k_scan3(const int* __restrict__ cnt,
                                                const int* __restrict__ boff,
                                                int* __restrict__ rowptr,
                                                int* __restrict__ cursor,
                                                float* __restrict__ dis,
                                                int* __restrict__ csr, int n) {
  __shared__ int wsum[16];
  int tid = threadIdx.x;
  int gid = blockIdx.x * 1024 + tid;
  int lane = tid & 63, wave = tid >> 6;
  int v = (gid < n) ? cnt[gid] : 0;
  int incl = v;
#pragma unroll
  for (int off = 1; off < 64; off <<= 1) {
    int t = __shfl_up(incl, off);
    if (lane >= off) incl += t;
  }
  if (lane == 63) wsum[wave] = incl;
  __syncthreads();
  if (tid < 16) {
    int s = wsum[tid];
    int is = s;
#pragma unroll
    for (int off = 1; off < 16; off <<= 1) {
      int t = __shfl_up(is, off, 16);
      if (tid >= off) is += t;
    }
    wsum[tid] = is - s;   // exclusive wave offset within block
  }
  __syncthreads();
  if (gid < n) {
    int exc = boff[blockIdx.x] + wsum[wave] + incl - v;
    rowptr[gid] = exc;
    cursor[gid] = exc + 1;       // slot 0 taken by self-loop
    csr[exc] = gid;              // self-loop entry
    dis[gid] = rsqrtf((float)v); // v >= 1 (self-loop)
  }
}

// Fill CSR: 4 edges/thread (round-7 lesson: need BOTH a dense grid AND
// multiple independent atomic->store chains; 8/thread starved occupancy).
__global__ void k_fill(const int* __restrict__ src, const int* __restrict__ dst,
                       int* __restrict__ cursor, int* __restrict__ csr, int e) {
  int i0 = (blockIdx.x * blockDim.x + threadIdx.x) * 4;
  if (i0 + 3 < e) {
    int4 s4 = *(const int4*)(src + i0);
    int4 d4 = *(const int4*)(dst + i0);
    int p0 = atomicAdd(&cursor[d4.x], 1);
    int p1 = atomicAdd(&cursor[d4.y], 1);
    int p2 = atomicAdd(&cursor[d4.z], 1);
    int p3 = atomicAdd(&cursor[d4.w], 1);
    csr[p0] = s4.x; csr[p1] = s4.y; csr[p2] = s4.z; csr[p3] = s4.w;
  } else {
    for (int i = i0; i < e; ++i) {
      int pos = atomicAdd(&cursor[dst[i]], 1);
      csr[pos] = src[i];
    }
  }
}

// ---------------------------------------------------------------------------
// Split-precision bf16 MFMA GEMM: t'[n x 128] = (A @ W) * dis[row], bf16 out.
// A@W = Ahi@Whi + Alo@Whi + Ahi@Wlo  (fp32 accum; lo*lo ~2^-18 dropped).
// Block 256 = 4 waves; wave owns 16 rows x 128 cols (8 col-frags, K=128).
// A frags straight from global (per row: 4 kgroups = contiguous 128B),
// W from pre-transposed bf16 Wt (L2-resident). Epilogue via swizzled LDS.
// ---------------------------------------------------------------------------
__global__ __launch_bounds__(256) void k_gemm_mfma(
    const float* __restrict__ A, const ushort16* __restrict__ Wth,
    const ushort16* __restrict__ Wtl, ushort16* __restrict__ Cb,
    const float* __restrict__ dis, int n) {
  __shared__ float sOut[64 * 128];
  const int tid = threadIdx.x;
  const int wv = tid >> 6;
  const int l = tid & 63;
  const int lr = l & 15;           // A-row / B-col within fragment
  const int kg = l >> 4;           // k-group (8 elems each)
  const int row0 = blockIdx.x * 64;
  const int arow = row0 + wv * 16 + lr;

  // ---- load A (4 ksteps x 8 fp32), split to bf16 hi/lo fragments ----
  float4 av[4][2];
  if (arow < n) {
    const float* ap = A + (size_t)arow * HDIM + kg * 8;
#pragma unroll
    for (int ks = 0; ks < 4; ++ks) {
      av[ks][0] = *(const float4*)(ap + ks * 32);
      av[ks][1] = *(const float4*)(ap + ks * 32 + 4);
    }
  } else {
#pragma unroll
    for (int ks = 0; ks < 4; ++ks)
      av[ks][0] = av[ks][1] = make_float4(0.f, 0.f, 0.f, 0.f);
  }
  U4 ahi[4], alo[4];
#pragma unroll
  for (int ks = 0; ks < 4; ++ks) {
    float f[8] = {av[ks][0].x, av[ks][0].y, av[ks][0].z, av[ks][0].w,
                  av[ks][1].x, av[ks][1].y, av[ks][1].z, av[ks][1].w};
    uint32 h[8], lo[8];
#pragma unroll
    for (int j = 0; j < 8; ++j) {
      uint32 u = __float_as_uint(f[j]);
      uint32 r = u + 0x7FFFu + ((u >> 16) & 1u);
      h[j] = r >> 16;
      float hf = __uint_as_float((r >> 16) << 16);
      lo[j] = (uint32)f2bf_rne(f[j] - hf);
    }
    ahi[ks].u = make_uint4(h[0] | (h[1] << 16), h[2] | (h[3] << 16),
                           h[4] | (h[5] << 16), h[6] | (h[7] << 16));
    alo[ks].u = make_uint4(lo[0] | (lo[1] << 16), lo[2] | (lo[3] << 16),
                           lo[4] | (lo[5] << 16), lo[6] | (lo[7] << 16));
  }

  f32x4 acc[8];
#pragma unroll
  for (int nc = 0; nc < 8; ++nc) acc[nc] = (f32x4){0.f, 0.f, 0.f, 0.f};

  // ---- MFMA main: 2 col-frags in flight for acc-chain ILP ----
#pragma unroll
  for (int nc = 0; nc < 8; nc += 2) {
    U4 w0h[4], w0l[4], w1h[4], w1l[4];
    const size_t c0 = (size_t)(nc * 16 + lr) * HDIM + kg * 8;
    const size_t c1 = (size_t)((nc + 1) * 16 + lr) * HDIM + kg * 8;
#pragma unroll
    for (int ks = 0; ks < 4; ++ks) {
      w0h[ks].u = *(const uint4*)(Wth + c0 + ks * 32);
      w0l[ks].u = *(const uint4*)(Wtl + c0 + ks * 32);
      w1h[ks].u = *(const uint4*)(Wth + c1 + ks * 32);
      w1l[ks].u = *(const uint4*)(Wtl + c1 + ks * 32);
    }
#pragma unroll
    for (int ks = 0; ks < 4; ++ks) {
      acc[nc]     = __builtin_amdgcn_mfma_f32_16x16x32_bf16(ahi[ks].v, w0h[ks].v, acc[nc],     0, 0, 0);
      acc[nc + 1] = __builtin_amdgcn_mfma_f32_16x16x32_bf16(ahi[ks].v, w1h[ks].v, acc[nc + 1], 0, 0, 0);
      acc[nc]     = __builtin_amdgcn_mfma_f32_16x16x32_bf16(alo[ks].v, w0h[ks].v, acc[nc],     0, 0, 0);
      acc[nc + 1] = __builtin_amdgcn_mfma_f32_16x16x32_bf16(alo[ks].v, w1h[ks].v, acc[nc + 1], 0, 0, 0);
      acc[nc]     = __builtin_amdgcn_mfma_f32_16x16x32_bf16(ahi[ks].v, w0l[ks].v, acc[nc],     0, 0, 0);
      acc[nc + 1] = __builtin_amdgcn_mfma_f32_16x16x32_bf16(ahi[ks].v, w1l[ks].v, acc[nc + 1], 0, 0, 0);
    }
  }

  // ---- epilogue: acc -> LDS (16B-chunk XOR swizzle balances banks) ----
#pragma unroll
  for (int nc = 0; nc < 8; ++nc) {
#pragma unroll
    for (int j = 0; j < 4; ++j) {
      int row = wv * 16 + kg * 4 + j;          // C/D: col=lane&15, row=kg*4+j
      int fc = nc * 16 + lr;
      int q = fc >> 5;
      int pw = (fc >> 2) & 7;
      sOut[row * 128 + q * 32 + ((pw ^ (row & 7)) << 2) + (fc & 3)] = acc[nc][j];
    }
  }
  __syncthreads();

  // ---- stream out: x dis, fp32 -> bf16, fully coalesced uint4 stores ----
  {
    int row = tid >> 2, q = tid & 3;
    int grow = row0 + row;
    if (grow < n) {
      float ds = dis[grow];
      ushort16* op = Cb + (size_t)grow * HDIM + q * 32;
#pragma unroll
      for (int p = 0; p < 8; p += 2) {
        float4 x0 = *(const float4*)(&sOut[row * 128 + q * 32 + ((p ^ (row & 7)) << 2)]);
        float4 x1 = *(const float4*)(&sOut[row * 128 + q * 32 + (((p + 1) ^ (row & 7)) << 2)]);
        uint4 pk;
        pk.x = (uint32)f2bf_rne(x0.x * ds) | ((uint32)f2bf_rne(x0.y * ds) << 16);
        pk.y = (uint32)f2bf_rne(x0.z * ds) | ((uint32)f2bf_rne(x0.w * ds) << 16);
        pk.z = (uint32)f2bf_rne(x1.x * ds) | ((uint32)f2bf_rne(x1.y * ds) << 16);
        pk.w = (uint32)f2bf_rne(x1.z * ds) | ((uint32)f2bf_rne(x1.w * ds) << 16);
        *(uint4*)(op + p * 4) = pk;
      }
    }
  }
}

// ---------------------------------------------------------------------------
// Tiled fp32 VALU GEMM (kept for the 64-col lin_w accumulate into out).
// ---------------------------------------------------------------------------
template <int COLS>
__global__ __launch_bounds__(256) void k_gemm(const float* __restrict__ A,
                                              const float* __restrict__ B,
                                              float* __restrict__ C, int n) {
  constexpr int KC = 32;
  constexpr int LDA = 132;
  constexpr int CPT = COLS / 16;
  __shared__ float sA[KC * LDA];
  __shared__ float sB[KC * COLS];
  const int tid = threadIdx.x;
  const int cg = tid & 15;
  const int rgb = tid >> 4;
  const int row0 = blockIdx.x * 128;

  float acc[8][CPT];
#pragma unroll
  for (int i = 0; i < 8; ++i)
#pragma unroll
    for (int j = 0; j < CPT; ++j) acc[i][j] = 0.f;

  const int skq = tid & 7;
  const int sr = tid >> 3;

  for (int kc = 0; kc < HDIM; kc += KC) {
    __syncthreads();
#pragma unroll
    for (int j = 0; j < 4; ++j) {
      int row = sr + 32 * j;
      int grow = row0 + row;
      float4 v = make_float4(0.f, 0.f, 0.f, 0.f);
      if (grow < n) v = *(const float4*)(A + (size_t)grow * HDIM + kc + skq * 4);
      int kl = skq * 4;
      sA[(kl + 0) * LDA + (row ^ (((kl + 0) & 7) << 2))] = v.x;
      sA[(kl + 1) * LDA + (row ^ (((kl + 1) & 7) << 2))] = v.y;
      sA[(kl + 2) * LDA + (row ^ (((kl + 2) & 7) << 2))] = v.z;
      sA[(kl + 3) * LDA + (row ^ (((kl + 3) & 7) << 2))] = v.w;
    }
    constexpr int NV = KC * COLS / 4;
#pragma unroll
    for (int v4 = tid; v4 < NV; v4 += 256) {
      int k = v4 / (COLS / 4);
      int c4 = (v4 - k * (COLS / 4)) * 4;
      float4 w = *(const float4*)(B + (size_t)(kc + k) * COLS + c4);
      int cp = c4 ^ (((c4 >> 5) & 3) << 2);
      *(float4*)(&sB[k * COLS + cp]) = w;
    }
    __syncthreads();
#pragma unroll 4
    for (int k = 0; k < KC; ++k) {
      int msk = (k & 7) << 2;
      float a[8];
      {
        float4 a0 = *(const float4*)(&sA[k * LDA + ((rgb * 8) ^ msk)]);
        float4 a1 = *(const float4*)(&sA[k * LDA + ((rgb * 8 + 4) ^ msk)]);
        a[0] = a0.x; a[1] = a0.y; a[2] = a0.z; a[3] = a0.w;
        a[4] = a1.x; a[5] = a1.y; a[6] = a1.z; a[7] = a1.w;
      }
      float b[CPT];
#pragma unroll
      for (int s = 0; s < CPT / 4; ++s) {
        int c0 = cg * CPT + s * 4;
        int cp = c0 ^ (((c0 >> 5) & 3) << 2);
        float4 w = *(const float4*)(&sB[k * COLS + cp]);
        b[s * 4 + 0] = w.x; b[s * 4 + 1] = w.y;
        b[s * 4 + 2] = w.z; b[s * 4 + 3] = w.w;
      }
#pragma unroll
      for (int i = 0; i < 8; ++i)
#pragma unroll
        for (int j = 0; j < CPT; ++j) acc[i][j] = fmaf(a[i], b[j], acc[i][j]);
    }
  }
#pragma unroll
  for (int i = 0; i < 8; ++i) {
    int grow = row0 + rgb * 8 + i;
    if (grow < n) {
#pragma unroll
      for (int s = 0; s < CPT / 4; ++s) {
        float4 o;
        o.x = acc[i][s * 4 + 0]; o.y = acc[i][s * 4 + 1];
        o.z = acc[i][s * 4 + 2]; o.w = acc[i][s * 4 + 3];
        float* cp = C + (size_t)grow * COLS + cg * CPT + s * 4;
        float4 prev = *(const float4*)cp;
        o.x += prev.x; o.y += prev.y; o.z += prev.z; o.w += prev.w;
        *(float4*)cp = o;
      }
    }
  }
}

// ---------------------------------------------------------------------------
// CSR-gather aggregation over bf16 t' (= t * dis[src]). One wave per node;
// quarter-wave (16 lanes x 16B = one 256B bf16 row) per edge.
// hout[v] = relu( dis[v] * sum_{u in CSR[v]} t'[u] + bias )   (fp32 out)
// ---------------------------------------------------------------------------
__global__ __launch_bounds__(256) void k_agg(const ushort16* __restrict__ tb,
                                             const int* __restrict__ rowptr,
                                             const int* __restrict__ csr,
                                             const float* __restrict__ dis,
                                             const float* __restrict__ bias,
                                             float* __restrict__ hout, int n) {
  const int lane = threadIdx.x & 63;
  const int q = lane >> 4;
  const int fl = (lane & 15) * 8;
  const float4 bv0 = *(const float4*)(bias + fl);
  const float4 bv1 = *(const float4*)(bias + fl + 4);
  const int wid = blockIdx.x * 4 + (threadIdx.x >> 6);
  const int nw = gridDim.x * 4;
  for (int v = wid; v < n; v += nw) {
    const int e0 = rowptr[v];
    const int e1 = rowptr[v + 1];
    float a0 = 0.f, a1 = 0.f, a2 = 0.f, a3 = 0.f;
    float a4 = 0.f, a5 = 0.f, a6 = 0.f, a7 = 0.f;
    int e = e0;
    for (; e + 7 < e1; e += 8) {
      int uA = csr[e + q];
      int uB = csr[e + 4 + q];
      uint4 ta = *(const uint4*)(tb + ((size_t)uA << 7) + fl);
      uint4 tc = *(const uint4*)(tb + ((size_t)uB << 7) + fl);
      a0 += bf_lo(ta.x); a1 += bf_hi(ta.x);
      a2 += bf_lo(ta.y); a3 += bf_hi(ta.y);
      a4 += bf_lo(ta.z); a5 += bf_hi(ta.z);
      a6 += bf_lo(ta.w); a7 += bf_hi(ta.w);
      a0 += bf_lo(tc.x); a1 += bf_hi(tc.x);
      a2 += bf_lo(tc.y); a3 += bf_hi(tc.y);
      a4 += bf_lo(tc.z); a5 += bf_hi(tc.z);
      a6 += bf_lo(tc.w); a7 += bf_hi(tc.w);
    }
    for (; e < e1; e += 4) {
      int idx = e + q;
      if (idx < e1) {
        int u = csr[idx];
        uint4 ta = *(const uint4*)(tb + ((size_t)u << 7) + fl);
        a0 += bf_lo(ta.x); a1 += bf_hi(ta.x);
        a2 += bf_lo(ta.y); a3 += bf_hi(ta.y);
        a4 += bf_lo(ta.z); a5 += bf_hi(ta.z);
        a6 += bf_lo(ta.w); a7 += bf_hi(ta.w);
      }
    }
    a0 += __shfl_xor(a0, 32); a1 += __shfl_xor(a1, 32);
    a2 += __shfl_xor(a2, 32); a3 += __shfl_xor(a3, 32);
    a4 += __shfl_xor(a4, 32); a5 += __shfl_xor(a5, 32);
    a6 += __shfl_xor(a6, 32); a7 += __shfl_xor(a7, 32);
    a0 += __shfl_xor(a0, 16); a1 += __shfl_xor(a1, 16);
    a2 += __shfl_xor(a2, 16); a3 += __shfl_xor(a3, 16);
    a4 += __shfl_xor(a4, 16); a5 += __shfl_xor(a5, 16);
    a6 += __shfl_xor(a6, 16); a7 += __shfl_xor(a7, 16);
    if (q == 0) {
      const float dv = dis[v];
      float4 h0, h1;
      h0.x = fmaxf(fmaf(a0, dv, bv0.x), 0.f);
      h0.y = fmaxf(fmaf(a1, dv, bv0.y), 0.f);
      h0.z = fmaxf(fmaf(a2, dv, bv0.z), 0.f);
      h0.w = fmaxf(fmaf(a3, dv, bv0.w), 0.f);
      h1.x = fmaxf(fmaf(a4, dv, bv1.x), 0.f);
      h1.y = fmaxf(fmaf(a5, dv, bv1.y), 0.f);
      h1.z = fmaxf(fmaf(a6, dv, bv1.z), 0.f);
      h1.w = fmaxf(fmaf(a7, dv, bv1.w), 0.f);
      float* hp = hout + (size_t)v * HDIM + fl;
      *(float4*)hp = h0;
      *(float4*)(hp + 4) = h1;
    }
  }
}

// ---------------------------------------------------------------------------
extern "C" void kernel_launch(void* const* d_in, const int* in_sizes, int n_in,
                              void* d_out, int out_size, void* d_ws, size_t ws_size,
                              hipStream_t stream) {
  (void)n_in; (void)out_size; (void)ws_size;
  const float* x  = (const float*)d_in[0];
  const int*   ei = (const int*)d_in[1];
  const float* Ws = (const float*)d_in[2];
  const float* bs = (const float*)d_in[3];
  const float* lw = (const float*)d_in[4];
  const float* lb = (const float*)d_in[5];
  float* out = (float*)d_out;

  const int n = in_sizes[0] / HDIM;
  const int e = in_sizes[1] / 2;
  const int* src = ei;
  const int* dst = ei + e;
  const int nb = (n + 1023) / 1024;   // scan level-1 block count

  // workspace carve-out
  char* p = (char*)d_ws;
  auto take = [&](size_t bytes) {
    char* r = p;
    p += (bytes + 255) & ~(size_t)255;
    return (void*)r;
  };
  int*      cnt    = (int*)take((size_t)n * 4);
  int*      rowptr = (int*)take((size_t)(n + 1) * 4);
  int*      cursor = (int*)take((size_t)n * 4);
  float*    dis    = (float*)take((size_t)n * 4);
  int*      bsum   = (int*)take((size_t)nb * 4);
  int*      boff   = (int*)take((size_t)nb * 4);
  int*      csr    = (int*)take((size_t)(e + n) * 4);
  ushort16* tbuf   = (ushort16*)take((size_t)n * HDIM * 2);        // bf16 t'
  float*    hbuf   = (float*)take((size_t)n * HDIM * 4);
  ushort16* wth    = (ushort16*)take((size_t)NLAYERS * HDIM * HDIM * 2);
  ushort16* wtl    = (ushort16*)take((size_t)NLAYERS * HDIM * HDIM * 2);

  // CSR build + W transpose/split (once)
  k_wprep<<<NLAYERS, 256, 0, stream>>>(Ws, wth, wtl);
  k_prep<<<1024, 256, 0, stream>>>(cnt, out, lb, n);
  k_count<<<((e + 3) / 4 + 255) / 256, 256, 0, stream>>>(dst, cnt, e);
  k_scan1<<<nb, 1024, 0, stream>>>(cnt, bsum, n);
  k_scan2<<<1, 64, 0, stream>>>(bsum, boff, rowptr, nb, n);
  k_scan3<<<nb, 1024, 0, stream>>>(cnt, boff, rowptr, cursor, dis, csr, n);
  k_fill<<<((e + 3) / 4 + 255) / 256, 256, 0, stream>>>(src, dst, cursor, csr, e);

  // 3 GCN layers; output projection fused per layer (out pre-seeded with lin_b)
  const int mtiles = (n + 63) / 64;
  const int gtiles = (n + 127) / 128;
  const float* hin = x;
  for (int l = 0; l < NLAYERS; ++l) {
    k_gemm_mfma<<<mtiles, 256, 0, stream>>>(
        hin, wth + (size_t)l * HDIM * HDIM, wtl + (size_t)l * HDIM * HDIM,
        tbuf, dis, n);
    k_agg<<<2048, 256, 0, stream>>>(
        tbuf, rowptr, csr, dis, bs + (size_t)l * HDIM, hbuf, n);
    k_gemm<RDIM><<<gtiles, 256, 0, stream>>>(
        hbuf, lw + (size_t)l * HDIM * RDIM, out, n);
    hin = hbuf;
  }
}

// Round 9
// 607.173 us; speedup vs baseline: 1.2540x; 1.2540x over previous
//
#include <hip/hip_runtime.h>

#define HDIM 128
#define RDIM 64
#define NLAYERS 3

typedef unsigned int uint32;
typedef unsigned short ushort16;

typedef __attribute__((ext_vector_type(8))) short s16x8;   // 8 bf16 (4 VGPR)
typedef __attribute__((ext_vector_type(4))) float f32x4;   // MFMA acc

union U4 { uint4 u; s16x8 v; };

// round-to-nearest-even fp32 -> bf16 (as raw ushort)
__device__ __forceinline__ ushort16 f2bf_rne(float x) {
  uint32 u = __float_as_uint(x);
  u += 0x7FFFu + ((u >> 16) & 1u);
  return (ushort16)(u >> 16);
}
__device__ __forceinline__ float bf_lo(uint32 p) { return __uint_as_float(p << 16); }
__device__ __forceinline__ float bf_hi(uint32 p) { return __uint_as_float(p & 0xFFFF0000u); }

// ---------------------------------------------------------------------------
// Phase 0: init degree counts (self-loop => 1) and out (= lin_b broadcast)
// ---------------------------------------------------------------------------
__global__ void k_prep(int* __restrict__ cnt, float* __restrict__ out,
                       const float* __restrict__ lin_b, int n) {
  int stride = gridDim.x * blockDim.x;
  int i0 = blockIdx.x * blockDim.x + threadIdx.x;
  for (int i = i0; i < n; i += stride) cnt[i] = 1;
  int total = n * RDIM;
  for (int i = i0; i < total; i += stride) out[i] = lin_b[i & (RDIM - 1)];
}

// W -> transposed split-bf16 (Wt_hi/Wt_lo [c][k]) for the MFMA GEMM.
__global__ void k_wprep(const float* __restrict__ Ws, ushort16* __restrict__ Wth,
                        ushort16* __restrict__ Wtl) {
  const int lyr = blockIdx.x;
  const float* W = Ws + (size_t)lyr * HDIM * HDIM;
  ushort16* th = Wth + (size_t)lyr * HDIM * HDIM;
  ushort16* tl = Wtl + (size_t)lyr * HDIM * HDIM;
  for (int idx = threadIdx.x; idx < HDIM * HDIM; idx += blockDim.x) {
    int k = idx >> 7, c = idx & 127;
    float w = W[idx];
    uint32 u = __float_as_uint(w);
    uint32 r = u + 0x7FFFu + ((u >> 16) & 1u);
    float hf = __uint_as_float((r >> 16) << 16);
    th[c * HDIM + k] = (ushort16)(r >> 16);
    tl[c * HDIM + k] = f2bf_rne(w - hf);
  }
}

// 4 edges/thread, int4 loads (no-return atomics have no dependent chain).
__global__ void k_count(const int* __restrict__ dst, int* __restrict__ cnt, int e) {
  int i0 = (blockIdx.x * blockDim.x + threadIdx.x) * 4;
  if (i0 + 3 < e) {
    int4 d4 = *(const int4*)(dst + i0);
    atomicAdd(&cnt[d4.x], 1);
    atomicAdd(&cnt[d4.y], 1);
    atomicAdd(&cnt[d4.z], 1);
    atomicAdd(&cnt[d4.w], 1);
  } else {
    for (int i = i0; i < e; ++i) atomicAdd(&cnt[dst[i]], 1);
  }
}

// ---------------------------------------------------------------------------
// Two-level parallel exclusive scan over cnt[] -> rowptr/cursor (+ dis fused).
// ---------------------------------------------------------------------------
__global__ __launch_bounds__(1024) void k_scan1(const int* __restrict__ cnt,
                                                int* __restrict__ bsum, int n) {
  __shared__ int red[16];
  int tid = threadIdx.x;
  int gid = blockIdx.x * 1024 + tid;
  int v = (gid < n) ? cnt[gid] : 0;
#pragma unroll
  for (int off = 1; off < 64; off <<= 1) v += __shfl_xor(v, off);
  if ((tid & 63) == 0) red[tid >> 6] = v;
  __syncthreads();
  if (tid < 16) {
    int s = red[tid];
#pragma unroll
    for (int off = 1; off < 16; off <<= 1) s += __shfl_xor(s, off, 16);
    if (tid == 0) bsum[blockIdx.x] = s;
  }
}

__global__ __launch_bounds__(64) void k_scan2(const int* __restrict__ bsum,
                                              int* __restrict__ boff,
                                              int* __restrict__ rowptr,
                                              int nb, int n) {
  int lane = threadIdx.x;
  int carry = 0;
  for (int base = 0; base < nb; base += 64) {
    int i = base + lane;
    int v = (i < nb) ? bsum[i] : 0;
    int incl = v;
#pragma unroll
    for (int off = 1; off < 64; off <<= 1) {
      int t = __shfl_up(incl, off);
      if (lane >= off) incl += t;
    }
    if (i < nb) boff[i] = carry + incl - v;
    carry += __shfl(incl, 63);
  }
  if (lane == 0) rowptr[n] = carry;
}

// Level 3: rowptr/cursor/dis; self-loop pre-placed at slot 0 of each bucket.
__global__ __launch_bounds__(1024) void k_scan3(const int* __restrict__ cnt,
                                                const int* __restrict__ boff,
                                                int* __restrict__ rowptr,
                                                int* __restrict__ cursor,
                                                float* __restrict__ dis,
                                                int* __restrict__ csr, int n) {
  __shared__ int wsum[16];
  int tid = threadIdx.x;
  int gid = blockIdx.x * 1024 + tid;
  int lane = tid & 63, wave = tid >> 6;
  int v = (gid < n) ? cnt[gid] : 0;
  int incl = v;
#pragma unroll
  for (int off = 1; off < 64; off <<= 1) {
    int t = __shfl_up(incl, off);
    if (lane >= off) incl += t;
  }
  if (lane == 63) wsum[wave] = incl;
  __syncthreads();
  if (tid < 16) {
    int s = wsum[tid];
    int is = s;
#pragma unroll
    for (int off = 1; off < 16; off <<= 1) {
      int t = __shfl_up(is, off, 16);
      if (tid >= off) is += t;
    }
    wsum[tid] = is - s;   // exclusive wave offset within block
  }
  __syncthreads();
  if (gid < n) {
    int exc = boff[blockIdx.x] + wsum[wave] + incl - v;
    rowptr[gid] = exc;
    cursor[gid] = exc + 1;       // slot 0 taken by self-loop
    csr[exc] = gid;              // self-loop entry
    dis[gid] = rsqrtf((float)v); // v >= 1 (self-loop)
  }
}

// Fill CSR, WINDOWED: only edges with dst in [lo,hi) are scattered this pass.
// Window ~1.7MB (n/4 nodes) stays L2-resident, so 64B lines accumulate ~16
// entries before write-back (round-8 lesson: full-range scatter = one full
// line write-back PER 4B entry, 106MB for a 6.8MB payload, capacity-bound).
__global__ void k_fill(const int* __restrict__ src, const int* __restrict__ dst,
                       int* __restrict__ cursor, int* __restrict__ csr,
                       int e, int lo, int hi) {
  int i0 = (blockIdx.x * blockDim.x + threadIdx.x) * 4;
  if (i0 + 3 < e) {
    int4 d4 = *(const int4*)(dst + i0);
    int4 s4 = *(const int4*)(src + i0);
    if (d4.x >= lo && d4.x < hi) { int p = atomicAdd(&cursor[d4.x], 1); csr[p] = s4.x; }
    if (d4.y >= lo && d4.y < hi) { int p = atomicAdd(&cursor[d4.y], 1); csr[p] = s4.y; }
    if (d4.z >= lo && d4.z < hi) { int p = atomicAdd(&cursor[d4.z], 1); csr[p] = s4.z; }
    if (d4.w >= lo && d4.w < hi) { int p = atomicAdd(&cursor[d4.w], 1); csr[p] = s4.w; }
  } else {
    for (int i = i0; i < e; ++i) {
      int d = dst[i];
      if (d >= lo && d < hi) { int p = atomicAdd(&cursor[d], 1); csr[p] = src[i]; }
    }
  }
}

// ---------------------------------------------------------------------------
// Split-precision bf16 MFMA GEMM: t'[n x 128] = (A @ W) * dis[row], bf16 out.
// A@W = Ahi@Whi + Alo@Whi + Ahi@Wlo  (fp32 accum; lo*lo ~2^-18 dropped).
// Round-9: W staged in LDS (coalesced global loads, chunk-XOR swizzle ->
// 2-way-max bank aliasing on ds_read_b128 = free). A direct from global.
// sOut epilogue tile ALIASES the W region after a barrier (LDS total 64KB,
// 2 blocks/CU). Round-8 lesson: register fragments straight from global are
// 16-way uncoalesced -> VMEM-transaction-bound.
// ---------------------------------------------------------------------------
__global__ __launch_bounds__(256) void k_gemm_mfma(
    const float* __restrict__ A, const ushort16* __restrict__ Wth,
    const ushort16* __restrict__ Wtl, ushort16* __restrict__ Cb,
    const float* __restrict__ dis, int n) {
  __shared__ uint4 ldsbuf[4096];           // 64 KB: sW[2][128][16] / sOut 32KB
  uint4* sW = ldsbuf;
  float* sOut = (float*)ldsbuf;

  const int tid = threadIdx.x;
  const int wv = tid >> 6;
  const int l = tid & 63;
  const int lr = l & 15;           // A-row / B-col within fragment
  const int kg = l >> 4;           // k-group (8 elems each)
  const int row0 = blockIdx.x * 64;
  const int arow = row0 + wv * 16 + lr;

  // ---- stage W hi/lo into LDS (coalesced; chunk' = chunk ^ (c&15)) ----
  {
    const uint4* gh = (const uint4*)Wth;
    const uint4* gl = (const uint4*)Wtl;
#pragma unroll
    for (int it = 0; it < 8; ++it) {
      int g = it * 256 + tid;          // [0,2048): c = g>>4, chunk = g&15
      int c = g >> 4, ch = g & 15;
      int chs = ch ^ (c & 15);
      sW[c * 16 + chs] = gh[g];
      sW[2048 + c * 16 + chs] = gl[g];
    }
  }

  // ---- load A (4 ksteps x 8 fp32), split to bf16 hi/lo fragments ----
  float4 av[4][2];
  if (arow < n) {
    const float* ap = A + (size_t)arow * HDIM + kg * 8;
#pragma unroll
    for (int ks = 0; ks < 4; ++ks) {
      av[ks][0] = *(const float4*)(ap + ks * 32);
      av[ks][1] = *(const float4*)(ap + ks * 32 + 4);
    }
  } else {
#pragma unroll
    for (int ks = 0; ks < 4; ++ks)
      av[ks][0] = av[ks][1] = make_float4(0.f, 0.f, 0.f, 0.f);
  }
  U4 ahi[4], alo[4];
#pragma unroll
  for (int ks = 0; ks < 4; ++ks) {
    float f[8] = {av[ks][0].x, av[ks][0].y, av[ks][0].z, av[ks][0].w,
                  av[ks][1].x, av[ks][1].y, av[ks][1].z, av[ks][1].w};
    uint32 h[8], lo[8];
#pragma unroll
    for (int j = 0; j < 8; ++j) {
      uint32 u = __float_as_uint(f[j]);
      uint32 r = u + 0x7FFFu + ((u >> 16) & 1u);
      h[j] = r >> 16;
      float hf = __uint_as_float((r >> 16) << 16);
      lo[j] = (uint32)f2bf_rne(f[j] - hf);
    }
    ahi[ks].u = make_uint4(h[0] | (h[1] << 16), h[2] | (h[3] << 16),
                           h[4] | (h[5] << 16), h[6] | (h[7] << 16));
    alo[ks].u = make_uint4(lo[0] | (lo[1] << 16), lo[2] | (lo[3] << 16),
                           lo[4] | (lo[5] << 16), lo[6] | (lo[7] << 16));
  }

  __syncthreads();   // W staged

  f32x4 acc[8];
#pragma unroll
  for (int nc = 0; nc < 8; ++nc) acc[nc] = (f32x4){0.f, 0.f, 0.f, 0.f};

  // ---- MFMA main: W frags via swizzled ds_read; 2 col-frags in flight ----
#pragma unroll
  for (int nc = 0; nc < 8; nc += 2) {
    U4 w0h[4], w0l[4], w1h[4], w1l[4];
    const int c0 = (nc * 16 + lr) * 16;
    const int c1 = ((nc + 1) * 16 + lr) * 16;
#pragma unroll
    for (int ks = 0; ks < 4; ++ks) {
      int chs = (kg + ks * 4) ^ lr;      // (c&15) == lr for both c0,c1
      w0h[ks].u = sW[c0 + chs];
      w0l[ks].u = sW[2048 + c0 + chs];
      w1h[ks].u = sW[c1 + chs];
      w1l[ks].u = sW[2048 + c1 + chs];
    }
#pragma unroll
    for (int ks = 0; ks < 4; ++ks) {
      acc[nc]     = __builtin_amdgcn_mfma_f32_16x16x32_bf16(ahi[ks].v, w0h[ks].v, acc[nc],     0, 0, 0);
      acc[nc + 1] = __builtin_amdgcn_mfma_f32_16x16x32_bf16(ahi[ks].v, w1h[ks].v, acc[nc + 1], 0, 0, 0);
      acc[nc]     = __builtin_amdgcn_mfma_f32_16x16x32_bf16(alo[ks].v, w0h[ks].v, acc[nc],     0, 0, 0);
      acc[nc + 1] = __builtin_amdgcn_mfma_f32_16x16x32_bf16(alo[ks].v, w1h[ks].v, acc[nc + 1], 0, 0, 0);
      acc[nc]     = __builtin_amdgcn_mfma_f32_16x16x32_bf16(ahi[ks].v, w0l[ks].v, acc[nc],     0, 0, 0);
      acc[nc + 1] = __builtin_amdgcn_mfma_f32_16x16x32_bf16(ahi[ks].v, w1l[ks].v, acc[nc + 1], 0, 0, 0);
    }
  }

  __syncthreads();   // all W reads done; safe to overwrite with sOut

  // ---- epilogue: acc -> LDS (16B-chunk XOR swizzle balances banks) ----
#pragma unroll
  for (int nc = 0; nc < 8; ++nc) {
#pragma unroll
    for (int j = 0; j < 4; ++j) {
      int row = wv * 16 + kg * 4 + j;          // C/D: col=lane&15, row=kg*4+j
      int fc = nc * 16 + lr;
      int q = fc >> 5;
      int pw = (fc >> 2) & 7;
      sOut[row * 128 + q * 32 + ((pw ^ (row & 7)) << 2) + (fc & 3)] = acc[nc][j];
    }
  }
  __syncthreads();

  // ---- stream out: x dis, fp32 -> bf16, fully coalesced uint4 stores ----
  {
    int row = tid >> 2, q = tid & 3;
    int grow = row0 + row;
    if (grow < n) {
      float ds = dis[grow];
      ushort16* op = Cb + (size_t)grow * HDIM + q * 32;
#pragma unroll
      for (int p = 0; p < 8; p += 2) {
        float4 x0 = *(const float4*)(&sOut[row * 128 + q * 32 + ((p ^ (row & 7)) << 2)]);
        float4 x1 = *(const float4*)(&sOut[row * 128 + q * 32 + (((p + 1) ^ (row & 7)) << 2)]);
        uint4 pk;
        pk.x = (uint32)f2bf_rne(x0.x * ds) | ((uint32)f2bf_rne(x0.y * ds) << 16);
        pk.y = (uint32)f2bf_rne(x0.z * ds) | ((uint32)f2bf_rne(x0.w * ds) << 16);
        pk.z = (uint32)f2bf_rne(x1.x * ds) | ((uint32)f2bf_rne(x1.y * ds) << 16);
        pk.w = (uint32)f2bf_rne(x1.z * ds) | ((uint32)f2bf_rne(x1.w * ds) << 16);
        *(uint4*)(op + p * 4) = pk;
      }
    }
  }
}

// ---------------------------------------------------------------------------
// Tiled fp32 VALU GEMM (kept for the 64-col lin_w accumulate into out).
// ---------------------------------------------------------------------------
template <int COLS>
__global__ __launch_bounds__(256) void k_gemm(const float* __restrict__ A,
                                              const float* __restrict__ B,
                                              float* __restrict__ C, int n) {
  constexpr int KC = 32;
  constexpr int LDA = 132;
  constexpr int CPT = COLS / 16;
  __shared__ float sA[KC * LDA];
  __shared__ float sB[KC * COLS];
  const int tid = threadIdx.x;
  const int cg = tid & 15;
  const int rgb = tid >> 4;
  const int row0 = blockIdx.x * 128;

  float acc[8][CPT];
#pragma unroll
  for (int i = 0; i < 8; ++i)
#pragma unroll
    for (int j = 0; j < CPT; ++j) acc[i][j] = 0.f;

  const int skq = tid & 7;
  const int sr = tid >> 3;

  for (int kc = 0; kc < HDIM; kc += KC) {
    __syncthreads();
#pragma unroll
    for (int j = 0; j < 4; ++j) {
      int row = sr + 32 * j;
      int grow = row0 + row;
      float4 v = make_float4(0.f, 0.f, 0.f, 0.f);
      if (grow < n) v = *(const float4*)(A + (size_t)grow * HDIM + kc + skq * 4);
      int kl = skq * 4;
      sA[(kl + 0) * LDA + (row ^ (((kl + 0) & 7) << 2))] = v.x;
      sA[(kl + 1) * LDA + (row ^ (((kl + 1) & 7) << 2))] = v.y;
      sA[(kl + 2) * LDA + (row ^ (((kl + 2) & 7) << 2))] = v.z;
      sA[(kl + 3) * LDA + (row ^ (((kl + 3) & 7) << 2))] = v.w;
    }
    constexpr int NV = KC * COLS / 4;
#pragma unroll
    for (int v4 = tid; v4 < NV; v4 += 256) {
      int k = v4 / (COLS / 4);
      int c4 = (v4 - k * (COLS / 4)) * 4;
      float4 w = *(const float4*)(B + (size_t)(kc + k) * COLS + c4);
      int cp = c4 ^ (((c4 >> 5) & 3) << 2);
      *(float4*)(&sB[k * COLS + cp]) = w;
    }
    __syncthreads();
#pragma unroll 4
    for (int k = 0; k < KC; ++k) {
      int msk = (k & 7) << 2;
      float a[8];
      {
        float4 a0 = *(const float4*)(&sA[k * LDA + ((rgb * 8) ^ msk)]);
        float4 a1 = *(const float4*)(&sA[k * LDA + ((rgb * 8 + 4) ^ msk)]);
        a[0] = a0.x; a[1] = a0.y; a[2] = a0.z; a[3] = a0.w;
        a[4] = a1.x; a[5] = a1.y; a[6] = a1.z; a[7] = a1.w;
      }
      float b[CPT];
#pragma unroll
      for (int s = 0; s < CPT / 4; ++s) {
        int c0 = cg * CPT + s * 4;
        int cp = c0 ^ (((c0 >> 5) & 3) << 2);
        float4 w = *(const float4*)(&sB[k * COLS + cp]);
        b[s * 4 + 0] = w.x; b[s * 4 + 1] = w.y;
        b[s * 4 + 2] = w.z; b[s * 4 + 3] = w.w;
      }
#pragma unroll
      for (int i = 0; i < 8; ++i)
#pragma unroll
        for (int j = 0; j < CPT; ++j) acc[i][j] = fmaf(a[i], b[j], acc[i][j]);
    }
  }
#pragma unroll
  for (int i = 0; i < 8; ++i) {
    int grow = row0 + rgb * 8 + i;
    if (grow < n) {
#pragma unroll
      for (int s = 0; s < CPT / 4; ++s) {
        float4 o;
        o.x = acc[i][s * 4 + 0]; o.y = acc[i][s * 4 + 1];
        o.z = acc[i][s * 4 + 2]; o.w = acc[i][s * 4 + 3];
        float* cp = C + (size_t)grow * COLS + cg * CPT + s * 4;
        float4 prev = *(const float4*)cp;
        o.x += prev.x; o.y += prev.y; o.z += prev.z; o.w += prev.w;
        *(float4*)cp = o;
      }
    }
  }
}

// ---------------------------------------------------------------------------
// CSR-gather aggregation over bf16 t' (= t * dis[src]). One wave per node;
// quarter-wave (16 lanes x 16B = one 256B bf16 row) per edge.
// hout[v] = relu( dis[v] * sum_{u in CSR[v]} t'[u] + bias )   (fp32 out)
// ---------------------------------------------------------------------------
__global__ __launch_bounds__(256) void k_agg(const ushort16* __restrict__ tb,
                                             const int* __restrict__ rowptr,
                                             const int* __restrict__ csr,
                                             const float* __restrict__ dis,
                                             const float* __restrict__ bias,
                                             float* __restrict__ hout, int n) {
  const int lane = threadIdx.x & 63;
  const int q = lane >> 4;
  const int fl = (lane & 15) * 8;
  const float4 bv0 = *(const float4*)(bias + fl);
  const float4 bv1 = *(const float4*)(bias + fl + 4);
  const int wid = blockIdx.x * 4 + (threadIdx.x >> 6);
  const int nw = gridDim.x * 4;
  for (int v = wid; v < n; v += nw) {
    const int e0 = rowptr[v];
    const int e1 = rowptr[v + 1];
    float a0 = 0.f, a1 = 0.f, a2 = 0.f, a3 = 0.f;
    float a4 = 0.f, a5 = 0.f, a6 = 0.f, a7 = 0.f;
    int e = e0;
    for (; e + 7 < e1; e += 8) {
      int uA = csr[e + q];
      int uB = csr[e + 4 + q];
      uint4 ta = *(const uint4*)(tb + ((size_t)uA << 7) + fl);
      uint4 tc = *(const uint4*)(tb + ((size_t)uB << 7) + fl);
      a0 += bf_lo(ta.x); a1 += bf_hi(ta.x);
      a2 += bf_lo(ta.y); a3 += bf_hi(ta.y);
      a4 += bf_lo(ta.z); a5 += bf_hi(ta.z);
      a6 += bf_lo(ta.w); a7 += bf_hi(ta.w);
      a0 += bf_lo(tc.x); a1 += bf_hi(tc.x);
      a2 += bf_lo(tc.y); a3 += bf_hi(tc.y);
      a4 += bf_lo(tc.z); a5 += bf_hi(tc.z);
      a6 += bf_lo(tc.w); a7 += bf_hi(tc.w);
    }
    for (; e < e1; e += 4) {
      int idx = e + q;
      if (idx < e1) {
        int u = csr[idx];
        uint4 ta = *(const uint4*)(tb + ((size_t)u << 7) + fl);
        a0 += bf_lo(ta.x); a1 += bf_hi(ta.x);
        a2 += bf_lo(ta.y); a3 += bf_hi(ta.y);
        a4 += bf_lo(ta.z); a5 += bf_hi(ta.z);
        a6 += bf_lo(ta.w); a7 += bf_hi(ta.w);
      }
    }
    a0 += __shfl_xor(a0, 32); a1 += __shfl_xor(a1, 32);
    a2 += __shfl_xor(a2, 32); a3 += __shfl_xor(a3, 32);
    a4 += __shfl_xor(a4, 32); a5 += __shfl_xor(a5, 32);
    a6 += __shfl_xor(a6, 32); a7 += __shfl_xor(a7, 32);
    a0 += __shfl_xor(a0, 16); a1 += __shfl_xor(a1, 16);
    a2 += __shfl_xor(a2, 16); a3 += __shfl_xor(a3, 16);
    a4 += __shfl_xor(a4, 16); a5 += __shfl_xor(a5, 16);
    a6 += __shfl_xor(a6, 16); a7 += __shfl_xor(a7, 16);
    if (q == 0) {
      const float dv = dis[v];
      float4 h0, h1;
      h0.x = fmaxf(fmaf(a0, dv, bv0.x), 0.f);
      h0.y = fmaxf(fmaf(a1, dv, bv0.y), 0.f);
      h0.z = fmaxf(fmaf(a2, dv, bv0.z), 0.f);
      h0.w = fmaxf(fmaf(a3, dv, bv0.w), 0.f);
      h1.x = fmaxf(fmaf(a4, dv, bv1.x), 0.f);
      h1.y = fmaxf(fmaf(a5, dv, bv1.y), 0.f);
      h1.z = fmaxf(fmaf(a6, dv, bv1.z), 0.f);
      h1.w = fmaxf(fmaf(a7, dv, bv1.w), 0.f);
      float* hp = hout + (size_t)v * HDIM + fl;
      *(float4*)hp = h0;
      *(float4*)(hp + 4) = h1;
    }
  }
}

// ---------------------------------------------------------------------------
extern "C" void kernel_launch(void* const* d_in, const int* in_sizes, int n_in,
                              void* d_out, int out_size, void* d_ws, size_t ws_size,
                              hipStream_t stream) {
  (void)n_in; (void)out_size; (void)ws_size;
  const float* x  = (const float*)d_in[0];
  const int*   ei = (const int*)d_in[1];
  const float* Ws = (const float*)d_in[2];
  const float* bs = (const float*)d_in[3];
  const float* lw = (const float*)d_in[4];
  const float* lb = (const float*)d_in[5];
  float* out = (float*)d_out;

  const int n = in_sizes[0] / HDIM;
  const int e = in_sizes[1] / 2;
  const int* src = ei;
  const int* dst = ei + e;
  const int nb = (n + 1023) / 1024;   // scan level-1 block count

  // workspace carve-out
  char* p = (char*)d_ws;
  auto take = [&](size_t bytes) {
    char* r = p;
    p += (bytes + 255) & ~(size_t)255;
    return (void*)r;
  };
  int*      cnt    = (int*)take((size_t)n * 4);
  int*      rowptr = (int*)take((size_t)(n + 1) * 4);
  int*      cursor = (int*)take((size_t)n * 4);
  float*    dis    = (float*)take((size_t)n * 4);
  int*      bsum   = (int*)take((size_t)nb * 4);
  int*      boff   = (int*)take((size_t)nb * 4);
  int*      csr    = (int*)take((size_t)(e + n) * 4);
  ushort16* tbuf   = (ushort16*)take((size_t)n * HDIM * 2);        // bf16 t'
  float*    hbuf   = (float*)take((size_t)n * HDIM * 4);
  ushort16* wth    = (ushort16*)take((size_t)NLAYERS * HDIM * HDIM * 2);
  ushort16* wtl    = (ushort16*)take((size_t)NLAYERS * HDIM * HDIM * 2);

  // CSR build + W transpose/split (once)
  k_wprep<<<NLAYERS, 256, 0, stream>>>(Ws, wth, wtl);
  k_prep<<<1024, 256, 0, stream>>>(cnt, out, lb, n);
  k_count<<<((e + 3) / 4 + 255) / 256, 256, 0, stream>>>(dst, cnt, e);
  k_scan1<<<nb, 1024, 0, stream>>>(cnt, bsum, n);
  k_scan2<<<1, 64, 0, stream>>>(bsum, boff, rowptr, nb, n);
  k_scan3<<<nb, 1024, 0, stream>>>(cnt, boff, rowptr, cursor, dis, csr, n);
  {
    const int PASSES = 4;
    const int rng = (n + PASSES - 1) / PASSES;
    const int fgrid = ((e + 3) / 4 + 255) / 256;
    for (int ps = 0; ps < PASSES; ++ps) {
      int lo = ps * rng;
      int hi = lo + rng < n ? lo + rng : n;
      k_fill<<<fgrid, 256, 0, stream>>>(src, dst, cursor, csr, e, lo, hi);
    }
  }

  // 3 GCN layers; output projection fused per layer (out pre-seeded with lin_b)
  const int mtiles = (n + 63) / 64;
  const int gtiles = (n + 127) / 128;
  const float* hin = x;
  for (int l = 0; l < NLAYERS; ++l) {
    k_gemm_mfma<<<mtiles, 256, 0, stream>>>(
        hin, wth + (size_t)l * HDIM * HDIM, wtl + (size_t)l * HDIM * HDIM,
        tbuf, dis, n);
    k_agg<<<2048, 256, 0, stream>>>(
        tbuf, rowptr, csr, dis, bs + (size_t)l * HDIM, hbuf, n);
    k_gemm<RDIM><<<gtiles, 256, 0, stream>>>(
        hbuf, lw + (size_t)l * HDIM * RDIM, out, n);
    hin = hbuf;
  }
}